// Round 14
// baseline (981.640 us; speedup 1.0000x reference)
//
#include <hip/hip_runtime.h>
#include <hip/hip_bf16.h>

// GroupedMLP: E=8, T=1024, H=2048, I=5632
// Round 13: kill the w1/w2 convert kernels (~300us, 1/3 of runtime; weights
// are single-use so ws-conversion is pure extra traffic). B is now reg-staged
// inside the ring-3 GEMM directly from fp32 weights: issue 8 k-strided dword
// loads of B(t+1) at tile-t start (T14 issue-early), vmcnt(2) at tile end
// (drains B(t+1)+A(t+1), leaves A(t+2) glds in flight), cvt+pack, swizzled
// ds_write_b128, lgkmcnt(0), barrier. A keeps global_load_lds 2-ahead from
// bf16 ws. LDS contents identical to r12 -> compute/epilogue unchanged.
// Geometry: 256x128 tile, BK=32, 8 waves of 64x64, 3x24KB LDS, 2 blocks/CU.

#define EXPERTS 8
#define TOK     1024
#define HID     2048
#define INTER   5632
#define I2      (2 * INTER)

typedef __bf16 bf16x8 __attribute__((ext_vector_type(8)));
typedef float  f32x4  __attribute__((ext_vector_type(4)));

#define G2(row) ((((row) >> 1) & 3) << 3)   // element-index XOR, bits 3-4

__device__ __forceinline__ unsigned short f2bf(float f) {
    union { float f; unsigned u; } v; v.f = f;
    unsigned r = v.u + 0x7FFFu + ((v.u >> 16) & 1u);   // RNE
    return (unsigned short)(r >> 16);
}

__device__ __forceinline__ void gload_lds16(const void* g, void* l) {
    __builtin_amdgcn_global_load_lds(
        (const __attribute__((address_space(1))) void*)g,
        (__attribute__((address_space(3))) void*)l, 16, 0, 0);
}

// fragment read from a [rows][32] bf16 tile, swizzled by G2(row)
__device__ __forceinline__ bf16x8 ldfrag(const unsigned short* S, int R, int kb) {
    int off = R * 32 + (kb ^ G2(R));
    return *reinterpret_cast<const bf16x8*>(S + off);
}

// ---------------- convert X only (G2-swizzled bf16 ws) ----------------

__global__ __launch_bounds__(256) void k_cvt_x(const float* __restrict__ X,
                                               unsigned short* __restrict__ Xb) {
    size_t base = ((size_t)blockIdx.x * 256 + threadIdx.x) * 8;
    int row = (int)(base >> 11);
    int k   = (int)(base & (HID - 1));
    int kp  = k ^ G2(row);
    float4 v0 = *reinterpret_cast<const float4*>(X + base);
    float4 v1 = *reinterpret_cast<const float4*>(X + base + 4);
    uint4 o;
    o.x = (unsigned)f2bf(v0.x) | ((unsigned)f2bf(v0.y) << 16);
    o.y = (unsigned)f2bf(v0.z) | ((unsigned)f2bf(v0.w) << 16);
    o.z = (unsigned)f2bf(v1.x) | ((unsigned)f2bf(v1.y) << 16);
    o.w = (unsigned)f2bf(v1.z) | ((unsigned)f2bf(v1.w) << 16);
    *reinterpret_cast<uint4*>(Xb + (size_t)row * HID + kp) = o;
}

// ---------------- ring-3 GEMM core with fused fp32 B-staging ----------------
// Buffer (24KB = 12288 ushorts): A [256][32] at 0, B [128][32] at +8192.
// A: 2 gload_lds16/thread, 2 tiles ahead. B: 8 k-strided fp32 dwords/thread,
// 1 tile ahead, cvt+ds_write_b128 at tile end.

template <int KTOT>
__device__ __forceinline__ void stageA(const unsigned short* Ab, int k0,
                                       unsigned short* buf, int t) {
#pragma unroll
    for (int j = 0; j < 2; ++j) {
        int lin = j * 512 + t;
        int row = lin >> 2;
        int col = (lin & 3) * 8;
        gload_lds16(Ab + (size_t)row * KTOT + k0 + col, buf + lin * 8);
    }
}

template <int LDW>
__device__ __forceinline__ void loadB(const float* W, int gcol, int k0, int kq8,
                                      float (&r)[8]) {
    const float* p = W + (size_t)(k0 + kq8) * LDW + gcol;
#pragma unroll
    for (int j = 0; j < 8; ++j) r[j] = p[(size_t)j * LDW];
}

__device__ __forceinline__ void writeB(unsigned short* Bl, int pcl, int kq8,
                                       float (&r)[8]) {
    uint4 o;
    o.x = (unsigned)f2bf(r[0]) | ((unsigned)f2bf(r[1]) << 16);
    o.y = (unsigned)f2bf(r[2]) | ((unsigned)f2bf(r[3]) << 16);
    o.z = (unsigned)f2bf(r[4]) | ((unsigned)f2bf(r[5]) << 16);
    o.w = (unsigned)f2bf(r[6]) | ((unsigned)f2bf(r[7]) << 16);
    *reinterpret_cast<uint4*>(Bl + pcl * 32 + (kq8 ^ G2(pcl))) = o;
}

#define MFMA_BF16(a, b, c) __builtin_amdgcn_mfma_f32_16x16x32_bf16(a, b, c, 0, 0, 0)

__device__ __forceinline__ void compute_tile(const unsigned short* Ac,
                                             const unsigned short* Bc,
                                             f32x4 (&acc)[4][4],
                                             int wr, int wc, int cl, int kb0) {
    bf16x8 b[4], a[2];
#pragma unroll
    for (int n = 0; n < 4; ++n)
        b[n] = ldfrag(Bc, wc + n * 16 + cl, kb0);
    a[0] = ldfrag(Ac, wr + cl, kb0);
#pragma unroll
    for (int m = 0; m < 4; ++m) {
        if (m < 3)
            a[(m + 1) & 1] = ldfrag(Ac, wr + (m + 1) * 16 + cl, kb0);
        __builtin_amdgcn_s_setprio(1);
#pragma unroll
        for (int n = 0; n < 4; ++n)
            acc[m][n] = MFMA_BF16(a[m & 1], b[n], acc[m][n]);
        __builtin_amdgcn_s_setprio(0);
    }
}

template <int KTOT, int LDW>
__device__ __forceinline__ void gemm_ring3(const unsigned short* Ab, const float* W,
                                           int gcol, f32x4 (&acc)[4][4],
                                           unsigned short* lds, int t, int lane,
                                           int wr, int wc) {
    const int cl  = lane & 15;
    const int kb0 = (lane >> 4) << 3;
    const int pcl = t & 127;
    const int kq8 = (t >> 7) * 8;
    const int nkt = KTOT / 32;

    unsigned short* p0 = lds;            // current
    unsigned short* p1 = lds + 12288;    // next (B write target)
    unsigned short* p2 = lds + 24576;    // next2 (A stage target)

    float r[8];
    // prologue: A(0), B(0), A(1); wait A(0)+B(0), leave A(1)'s 2 in flight
    stageA<KTOT>(Ab, 0, p0, t);
    loadB<LDW>(W, gcol, 0, kq8, r);
    stageA<KTOT>(Ab, 32, p1, t);
    asm volatile("s_waitcnt vmcnt(2)" ::: "memory");
    writeB(p0 + 8192, pcl, kq8, r);
    asm volatile("s_waitcnt lgkmcnt(0)" ::: "memory");
    __builtin_amdgcn_s_barrier();
    asm volatile("" ::: "memory");

    for (int kt = 0; kt < nkt; ++kt) {
        // issue-early: B(t+1) regs (oldest this tile), then A(t+2) glds (newest)
        if (kt + 1 < nkt) loadB<LDW>(W, gcol, (kt + 1) * 32, kq8, r);
        if (kt + 2 < nkt) stageA<KTOT>(Ab, (kt + 2) * 32, p2, t);

        compute_tile(p0, p0 + 8192, acc, wr, wc, cl, kb0);

        if (kt + 1 < nkt) {
            // drain everything except A(t+2)'s 2 glds (the 2 newest)
            if (kt + 2 < nkt) { asm volatile("s_waitcnt vmcnt(2)" ::: "memory"); }
            else              { asm volatile("s_waitcnt vmcnt(0)" ::: "memory"); }
            writeB(p1 + 8192, pcl, kq8, r);
            asm volatile("s_waitcnt lgkmcnt(0)" ::: "memory");
            __builtin_amdgcn_s_barrier();
            asm volatile("" ::: "memory");
        }
        unsigned short* tmp = p0; p0 = p1; p1 = p2; p2 = tmp;
    }
}

// fc1: Xb(bf16 ws) @ w1(fp32, native [H][2I]) -> inter bf16 (GLU fused)
__global__ __launch_bounds__(512, 4) void k_fc1_r4(const unsigned short* __restrict__ Xb,
                                                   const float* __restrict__ W1,
                                                   unsigned short* __restrict__ inter) {
    extern __shared__ unsigned short lds[];
    const int bid = blockIdx.x;                // 2816 = 8 XCD * (4 mt * 88 nt)
    const int e   = bid & 7;
    const int idx = bid >> 3;
    const int mt  = idx & 3;                   // mt innermost: B-panel shared
    const int nt  = idx >> 2;                  // 0..87
    const int t = threadIdx.x, lane = t & 63, w = t >> 6;
    const int wr = (w >> 1) * 64;
    const int wc = (w & 1) * 64;
    const int m0 = e * TOK + mt * 256;
    const int n0 = nt * 128;                   // pc-space
    const unsigned short* Ab = Xb + (size_t)m0 * HID;
    const float* W = W1 + (size_t)e * HID * I2;
    // per-thread B column: pc = n0+pcl -> native col = (pc&1)*I + (pc>>1)
    const int pc   = n0 + (t & 127);
    const int gcol = (pc & 1) * INTER + (pc >> 1);

    f32x4 acc[4][4];
#pragma unroll
    for (int i = 0; i < 4; ++i)
#pragma unroll
        for (int j = 0; j < 4; ++j) acc[i][j] = f32x4{0.f, 0.f, 0.f, 0.f};

    gemm_ring3<HID, I2>(Ab, W, gcol, acc, lds, t, lane, wr, wc);

    const int cl = lane & 15;
    const int r0 = (lane >> 4) << 2;
#pragma unroll
    for (int mf = 0; mf < 4; ++mf)
#pragma unroll
        for (int nf = 0; nf < 4; ++nf)
#pragma unroll
            for (int r = 0; r < 4; ++r) {
                float v  = acc[mf][nf][r];
                float pv = __shfl_xor(v, 1);
                if ((lane & 1) == 0) {
                    float s = v / (1.f + __expf(-v)) * pv;
                    int row = m0 + wr + mf * 16 + r0 + r;
                    int pcc = n0 + wc + nf * 16 + cl;
                    int c   = pcc >> 1;
                    int c2  = (c & ~31) | ((c & 31) ^ G2(row));  // fc2-A swizzle
                    inter[(size_t)row * INTER + c2] = f2bf(s);
                }
            }
}

// fc2: inter(bf16 ws) @ w2(fp32, native [I][H]) -> out fp32
__global__ __launch_bounds__(512, 4) void k_fc2_r4(const unsigned short* __restrict__ A,
                                                   const float* __restrict__ W2,
                                                   float* __restrict__ out) {
    extern __shared__ unsigned short lds[];
    const int bid = blockIdx.x;                // 512 = 8 XCD * (4 mt * 16 nt)
    const int e   = bid & 7;
    const int idx = bid >> 3;
    const int mt  = idx & 3;
    const int nt  = idx >> 2;                  // 0..15
    const int t = threadIdx.x, lane = t & 63, w = t >> 6;
    const int wr = (w >> 1) * 64;
    const int wc = (w & 1) * 64;
    const int m0 = e * TOK + mt * 256;
    const int n0 = nt * 128;
    const unsigned short* Ab = A + (size_t)m0 * INTER;
    const float* W = W2 + (size_t)e * INTER * HID;
    const int gcol = n0 + (t & 127);

    f32x4 acc[4][4];
#pragma unroll
    for (int i = 0; i < 4; ++i)
#pragma unroll
        for (int j = 0; j < 4; ++j) acc[i][j] = f32x4{0.f, 0.f, 0.f, 0.f};

    gemm_ring3<INTER, HID>(Ab, W, gcol, acc, lds, t, lane, wr, wc);

    const int cl = lane & 15;
    const int r0 = (lane >> 4) << 2;
#pragma unroll
    for (int mf = 0; mf < 4; ++mf)
#pragma unroll
        for (int nf = 0; nf < 4; ++nf)
#pragma unroll
            for (int r = 0; r < 4; ++r) {
                int row = m0 + wr + mf * 16 + r0 + r;
                int col = n0 + wc + nf * 16 + cl;
                out[(size_t)row * HID + col] = acc[mf][nf][r];
            }
}

// ---------------- fallback (round-1 kernels, need only 92 MB ws) ----------------

#define BM  128
#define BK  64
#define LDK 72

__global__ __launch_bounds__(256) void k_fc1_glu_fb(
    const float* __restrict__ X, const float* __restrict__ W1,
    unsigned short* __restrict__ inter)
{
    __shared__ unsigned short As[BM][LDK];
    __shared__ unsigned short Bs[128][LDK];
    const int bid = blockIdx.x;
    const int nt  = bid % (INTER / 64);
    const int mt  = (bid / (INTER / 64)) % (TOK / BM);
    const int e   = bid / ((INTER / 64) * (TOK / BM));
    const int t = threadIdx.x, lane = t & 63, w = t >> 6;
    const int m0 = mt * BM;
    const int rowbase = e * TOK + m0;
    f32x4 acc[2][8];
#pragma unroll
    for (int i = 0; i < 2; ++i)
#pragma unroll
        for (int jj = 0; jj < 8; ++jj) acc[i][jj] = f32x4{0.f, 0.f, 0.f, 0.f};
    const int jcol = t & 127;
    const int hf   = t >> 7;
    const int gcol = (jcol < 64) ? (nt * 64 + jcol) : (INTER + nt * 64 + (jcol - 64));
    const float* w1e = W1 + (size_t)e * HID * I2;
    for (int k0 = 0; k0 < HID; k0 += BK) {
#pragma unroll
        for (int it = 0; it < 8; ++it) {
            int lin = it * 256 + t;
            int r   = lin >> 4;
            int kq  = (lin & 15) << 2;
            const float4 v = *reinterpret_cast<const float4*>(
                X + (size_t)(rowbase + r) * HID + k0 + kq);
            ushort4 o;
            o.x = f2bf(v.x); o.y = f2bf(v.y); o.z = f2bf(v.z); o.w = f2bf(v.w);
            *reinterpret_cast<ushort4*>(&As[r][kq]) = o;
        }
#pragma unroll
        for (int it = 0; it < 8; ++it) {
            int kq = hf * 4 + it * 8;
            const float* p = w1e + (size_t)(k0 + kq) * I2 + gcol;
            float v0 = p[0], v1 = p[I2], v2 = p[2 * I2], v3 = p[3 * I2];
            ushort4 o;
            o.x = f2bf(v0); o.y = f2bf(v1); o.z = f2bf(v2); o.w = f2bf(v3);
            *reinterpret_cast<ushort4*>(&Bs[jcol][kq]) = o;
        }
        __syncthreads();
#pragma unroll
        for (int kk = 0; kk < 2; ++kk) {
            const int kb = kk * 32 + ((lane >> 4) << 3);
            bf16x8 a0 = *reinterpret_cast<const bf16x8*>(&As[w * 32 + (lane & 15)][kb]);
            bf16x8 a1 = *reinterpret_cast<const bf16x8*>(&As[w * 32 + 16 + (lane & 15)][kb]);
#pragma unroll
            for (int nf = 0; nf < 8; ++nf) {
                bf16x8 b = *reinterpret_cast<const bf16x8*>(&Bs[nf * 16 + (lane & 15)][kb]);
                acc[0][nf] = MFMA_BF16(a0, b, acc[0][nf]);
                acc[1][nf] = MFMA_BF16(a1, b, acc[1][nf]);
            }
        }
        __syncthreads();
    }
    const int rl0 = w * 32 + ((lane >> 4) << 2);
    const int cl  = lane & 15;
#pragma unroll
    for (int mf = 0; mf < 2; ++mf)
#pragma unroll
        for (int nfa = 0; nfa < 4; ++nfa) {
            f32x4 va = acc[mf][nfa];
            f32x4 vb = acc[mf][nfa + 4];
#pragma unroll
            for (int r = 0; r < 4; ++r) {
                float a = va[r], b = vb[r];
                float s = a / (1.f + __expf(-a)) * b;
                int row = rowbase + rl0 + mf * 16 + r;
                int col = nt * 64 + nfa * 16 + cl;
                inter[(size_t)row * INTER + col] = f2bf(s);
            }
        }
}

__global__ __launch_bounds__(256) void k_fc2_fb(
    const unsigned short* __restrict__ inter, const float* __restrict__ W2,
    float* __restrict__ out)
{
    __shared__ unsigned short As[BM][LDK];
    __shared__ unsigned short Bs[128][LDK];
    const int bid = blockIdx.x;
    const int nt  = bid % (HID / 128);
    const int mt  = (bid / (HID / 128)) % (TOK / BM);
    const int e   = bid / ((HID / 128) * (TOK / BM));
    const int t = threadIdx.x, lane = t & 63, w = t >> 6;
    const int m0 = mt * BM;
    const int rowbase = e * TOK + m0;
    f32x4 acc[2][8];
#pragma unroll
    for (int i = 0; i < 2; ++i)
#pragma unroll
        for (int jj = 0; jj < 8; ++jj) acc[i][jj] = f32x4{0.f, 0.f, 0.f, 0.f};
    const int jcol = t & 127;
    const int hf   = t >> 7;
    const int gcol = nt * 128 + jcol;
    const float* w2e = W2 + (size_t)e * INTER * HID;
    for (int k0 = 0; k0 < INTER; k0 += BK) {
#pragma unroll
        for (int it = 0; it < 4; ++it) {
            int lin = it * 256 + t;
            int r   = lin >> 3;
            int kq  = (lin & 7) << 3;
            uint4 v = *reinterpret_cast<const uint4*>(
                inter + (size_t)(rowbase + r) * INTER + k0 + kq);
            *reinterpret_cast<uint4*>(&As[r][kq]) = v;
        }
#pragma unroll
        for (int it = 0; it < 8; ++it) {
            int kq = hf * 4 + it * 8;
            const float* p = w2e + (size_t)(k0 + kq) * HID + gcol;
            float v0 = p[0], v1 = p[HID], v2 = p[2 * HID], v3 = p[3 * HID];
            ushort4 o;
            o.x = f2bf(v0); o.y = f2bf(v1); o.z = f2bf(v2); o.w = f2bf(v3);
            *reinterpret_cast<ushort4*>(&Bs[jcol][kq]) = o;
        }
        __syncthreads();
#pragma unroll
        for (int kk = 0; kk < 2; ++kk) {
            const int kb = kk * 32 + ((lane >> 4) << 3);
            bf16x8 a0 = *reinterpret_cast<const bf16x8*>(&As[w * 32 + (lane & 15)][kb]);
            bf16x8 a1 = *reinterpret_cast<const bf16x8*>(&As[w * 32 + 16 + (lane & 15)][kb]);
#pragma unroll
            for (int nf = 0; nf < 8; ++nf) {
                bf16x8 b = *reinterpret_cast<const bf16x8*>(&Bs[nf * 16 + (lane & 15)][kb]);
                acc[0][nf] = MFMA_BF16(a0, b, acc[0][nf]);
                acc[1][nf] = MFMA_BF16(a1, b, acc[1][nf]);
            }
        }
        __syncthreads();
    }
    const int rl0 = w * 32 + ((lane >> 4) << 2);
    const int cl  = lane & 15;
#pragma unroll
    for (int mf = 0; mf < 2; ++mf)
#pragma unroll
        for (int nf = 0; nf < 8; ++nf) {
            f32x4 v = acc[mf][nf];
#pragma unroll
            for (int r = 0; r < 4; ++r) {
                int row = rowbase + rl0 + mf * 16 + r;
                int col = nt * 128 + nf * 16 + cl;
                out[(size_t)row * HID + col] = v[r];
            }
        }
}

// ---------------- launch ----------------

extern "C" void kernel_launch(void* const* d_in, const int* in_sizes, int n_in,
                              void* d_out, int out_size, void* d_ws, size_t ws_size,
                              hipStream_t stream) {
    const float* X  = (const float*)d_in[0];
    const float* W1 = (const float*)d_in[1];
    const float* W2 = (const float*)d_in[2];
    float* out = (float*)d_out;

    const size_t XB_B  = (size_t)EXPERTS * TOK * HID * 2;        // 33.5 MB
    const size_t INT_B = (size_t)EXPERTS * TOK * INTER * 2;      // 92.3 MB
    const size_t need  = XB_B + INT_B;

    if (ws_size >= need) {
        unsigned short* Xb    = (unsigned short*)d_ws;
        unsigned short* inter = (unsigned short*)((char*)d_ws + XB_B);

        hipFuncSetAttribute((const void*)k_fc1_r4,
            hipFuncAttributeMaxDynamicSharedMemorySize, 73728);
        hipFuncSetAttribute((const void*)k_fc2_r4,
            hipFuncAttributeMaxDynamicSharedMemorySize, 73728);

        dim3 b256(256), b512(512);
        k_cvt_x <<<(EXPERTS * TOK * HID) / (256 * 8), b256, 0, stream>>>(X, Xb);
        k_fc1_r4<<<EXPERTS * 4 * (I2 / 128),  b512, 73728, stream>>>(Xb, W1, inter);
        k_fc2_r4<<<EXPERTS * 4 * (HID / 128), b512, 73728, stream>>>(inter, W2, out);
    } else {
        unsigned short* inter = (unsigned short*)d_ws;
        dim3 b256(256);
        k_fc1_glu_fb<<<EXPERTS * (TOK / BM) * (INTER / 64), b256, 0, stream>>>(X, W1, inter);
        k_fc2_fb    <<<EXPERTS * (TOK / BM) * (HID / 128),  b256, 0, stream>>>(inter, W2, out);
    }
}

// Round 15
// 852.875 us; speedup vs baseline: 1.1510x; 1.1510x over previous
//
#include <hip/hip_runtime.h>
#include <hip/hip_bf16.h>

// GroupedMLP: E=8, T=1024, H=2048, I=5632
// Round 14: r13's fused fp32-B staging (no w1/w2 convert kernels) with fc1's
// coalescing FIXED: thread's load-column decoupled from its LDS row. Threads
// 0-63 load contiguous 'a' cols, 64-127 contiguous 'b' cols (coalesced), and
// ds_write to the GLU-interleaved LDS row (2*tc / 2*(tc-64)+1), so LDS
// contents remain identical to r12's w1t layout (compute/epilogue unchanged).
// fc2 fused staging already validated in r13 (matched r12 fc2 while killing
// cvt_w2). Ring-3 invariants unchanged: vmcnt(2) leaves only A(t+2) glds in
// flight; writeB(t+1) -> lgkmcnt(0) -> barrier.

#define EXPERTS 8
#define TOK     1024
#define HID     2048
#define INTER   5632
#define I2      (2 * INTER)

typedef __bf16 bf16x8 __attribute__((ext_vector_type(8)));
typedef float  f32x4  __attribute__((ext_vector_type(4)));

#define G2(row) ((((row) >> 1) & 3) << 3)   // element-index XOR, bits 3-4

__device__ __forceinline__ unsigned short f2bf(float f) {
    union { float f; unsigned u; } v; v.f = f;
    unsigned r = v.u + 0x7FFFu + ((v.u >> 16) & 1u);   // RNE
    return (unsigned short)(r >> 16);
}

__device__ __forceinline__ void gload_lds16(const void* g, void* l) {
    __builtin_amdgcn_global_load_lds(
        (const __attribute__((address_space(1))) void*)g,
        (__attribute__((address_space(3))) void*)l, 16, 0, 0);
}

// fragment read from a [rows][32] bf16 tile, swizzled by G2(row)
__device__ __forceinline__ bf16x8 ldfrag(const unsigned short* S, int R, int kb) {
    int off = R * 32 + (kb ^ G2(R));
    return *reinterpret_cast<const bf16x8*>(S + off);
}

// ---------------- convert X only (G2-swizzled bf16 ws) ----------------

__global__ __launch_bounds__(256) void k_cvt_x(const float* __restrict__ X,
                                               unsigned short* __restrict__ Xb) {
    size_t base = ((size_t)blockIdx.x * 256 + threadIdx.x) * 8;
    int row = (int)(base >> 11);
    int k   = (int)(base & (HID - 1));
    int kp  = k ^ G2(row);
    float4 v0 = *reinterpret_cast<const float4*>(X + base);
    float4 v1 = *reinterpret_cast<const float4*>(X + base + 4);
    uint4 o;
    o.x = (unsigned)f2bf(v0.x) | ((unsigned)f2bf(v0.y) << 16);
    o.y = (unsigned)f2bf(v0.z) | ((unsigned)f2bf(v0.w) << 16);
    o.z = (unsigned)f2bf(v1.x) | ((unsigned)f2bf(v1.y) << 16);
    o.w = (unsigned)f2bf(v1.z) | ((unsigned)f2bf(v1.w) << 16);
    *reinterpret_cast<uint4*>(Xb + (size_t)row * HID + kp) = o;
}

// ---------------- ring-3 GEMM core with fused fp32 B-staging ----------------
// Buffer (24KB = 12288 ushorts): A [256][32] at 0, B [128][32] at +8192.
// A: 2 gload_lds16/thread, 2 tiles ahead. B: 8 coalesced k-strided fp32
// dwords/thread (column gcol), 1 tile ahead, cvt + swizzled ds_write_b128 to
// LDS row pcl at tile end.

template <int KTOT>
__device__ __forceinline__ void stageA(const unsigned short* Ab, int k0,
                                       unsigned short* buf, int t) {
#pragma unroll
    for (int j = 0; j < 2; ++j) {
        int lin = j * 512 + t;
        int row = lin >> 2;
        int col = (lin & 3) * 8;
        gload_lds16(Ab + (size_t)row * KTOT + k0 + col, buf + lin * 8);
    }
}

__device__ __forceinline__ void loadB(const float* W, size_t ldw, int gcol, int k0,
                                      int kq8, float (&r)[8]) {
    const float* p = W + (size_t)(k0 + kq8) * ldw + gcol;
#pragma unroll
    for (int j = 0; j < 8; ++j) r[j] = p[j * ldw];
}

__device__ __forceinline__ void writeB(unsigned short* Bl, int pcl, int kq8,
                                       float (&r)[8]) {
    uint4 o;
    o.x = (unsigned)f2bf(r[0]) | ((unsigned)f2bf(r[1]) << 16);
    o.y = (unsigned)f2bf(r[2]) | ((unsigned)f2bf(r[3]) << 16);
    o.z = (unsigned)f2bf(r[4]) | ((unsigned)f2bf(r[5]) << 16);
    o.w = (unsigned)f2bf(r[6]) | ((unsigned)f2bf(r[7]) << 16);
    *reinterpret_cast<uint4*>(Bl + pcl * 32 + (kq8 ^ G2(pcl))) = o;
}

#define MFMA_BF16(a, b, c) __builtin_amdgcn_mfma_f32_16x16x32_bf16(a, b, c, 0, 0, 0)

__device__ __forceinline__ void compute_tile(const unsigned short* Ac,
                                             const unsigned short* Bc,
                                             f32x4 (&acc)[4][4],
                                             int wr, int wc, int cl, int kb0) {
    bf16x8 b[4], a[2];
#pragma unroll
    for (int n = 0; n < 4; ++n)
        b[n] = ldfrag(Bc, wc + n * 16 + cl, kb0);
    a[0] = ldfrag(Ac, wr + cl, kb0);
#pragma unroll
    for (int m = 0; m < 4; ++m) {
        if (m < 3)
            a[(m + 1) & 1] = ldfrag(Ac, wr + (m + 1) * 16 + cl, kb0);
        __builtin_amdgcn_s_setprio(1);
#pragma unroll
        for (int n = 0; n < 4; ++n)
            acc[m][n] = MFMA_BF16(a[m & 1], b[n], acc[m][n]);
        __builtin_amdgcn_s_setprio(0);
    }
}

template <int KTOT>
__device__ __forceinline__ void gemm_ring3(const unsigned short* Ab, const float* W,
                                           size_t ldw, int gcol, int pcl,
                                           f32x4 (&acc)[4][4],
                                           unsigned short* lds, int t, int lane,
                                           int wr, int wc) {
    const int cl  = lane & 15;
    const int kb0 = (lane >> 4) << 3;
    const int kq8 = (t >> 7) * 8;
    const int nkt = KTOT / 32;

    unsigned short* p0 = lds;            // current
    unsigned short* p1 = lds + 12288;    // next (B write target)
    unsigned short* p2 = lds + 24576;    // next2 (A stage target)

    float r[8];
    // prologue: A(0), B(0), A(1); wait A(0)+B(0), leave A(1)'s 2 in flight
    stageA<KTOT>(Ab, 0, p0, t);
    loadB(W, ldw, gcol, 0, kq8, r);
    stageA<KTOT>(Ab, 32, p1, t);
    asm volatile("s_waitcnt vmcnt(2)" ::: "memory");
    writeB(p0 + 8192, pcl, kq8, r);
    asm volatile("s_waitcnt lgkmcnt(0)" ::: "memory");
    __builtin_amdgcn_s_barrier();
    asm volatile("" ::: "memory");

    for (int kt = 0; kt < nkt; ++kt) {
        // issue-early: B(t+1) regs (oldest this tile), then A(t+2) glds (newest)
        if (kt + 1 < nkt) loadB(W, ldw, gcol, (kt + 1) * 32, kq8, r);
        if (kt + 2 < nkt) stageA<KTOT>(Ab, (kt + 2) * 32, p2, t);

        compute_tile(p0, p0 + 8192, acc, wr, wc, cl, kb0);

        if (kt + 1 < nkt) {
            // drain everything except A(t+2)'s 2 glds (the 2 newest)
            if (kt + 2 < nkt) { asm volatile("s_waitcnt vmcnt(2)" ::: "memory"); }
            else              { asm volatile("s_waitcnt vmcnt(0)" ::: "memory"); }
            writeB(p1 + 8192, pcl, kq8, r);
            asm volatile("s_waitcnt lgkmcnt(0)" ::: "memory");
            __builtin_amdgcn_s_barrier();
            asm volatile("" ::: "memory");
        }
        unsigned short* tmp = p0; p0 = p1; p1 = p2; p2 = tmp;
    }
}

// fc1: Xb(bf16 ws) @ w1(fp32 native [H][2I]) -> inter bf16 (GLU fused)
__global__ __launch_bounds__(512, 4) void k_fc1_r4(const unsigned short* __restrict__ Xb,
                                                   const float* __restrict__ W1,
                                                   unsigned short* __restrict__ inter) {
    extern __shared__ unsigned short lds[];
    const int bid = blockIdx.x;                // 2816 = 8 XCD * (4 mt * 88 nt)
    const int e   = bid & 7;
    const int idx = bid >> 3;
    const int mt  = idx & 3;                   // mt innermost: B-panel shared
    const int nt  = idx >> 2;                  // 0..87
    const int t = threadIdx.x, lane = t & 63, w = t >> 6;
    const int wr = (w >> 1) * 64;
    const int wc = (w & 1) * 64;
    const int m0 = e * TOK + mt * 256;
    const int n0 = nt * 128;                   // pc-space
    const unsigned short* Ab = Xb + (size_t)m0 * HID;
    const float* W = W1 + (size_t)e * HID * I2;
    // COALESCED load mapping, decoupled from LDS row:
    //   threads 0-63 load contiguous 'a' cols, 64-127 contiguous 'b' cols;
    //   LDS row is the GLU-interleaved pc (even=a, odd=b).
    const int tc   = t & 127;
    const int nh   = n0 >> 1;                  // native col base
    const int gcol = (tc < 64) ? (nh + tc) : (INTER + nh + (tc - 64));
    const int pcl  = (tc < 64) ? (2 * tc) : (2 * (tc - 64) + 1);

    f32x4 acc[4][4];
#pragma unroll
    for (int i = 0; i < 4; ++i)
#pragma unroll
        for (int j = 0; j < 4; ++j) acc[i][j] = f32x4{0.f, 0.f, 0.f, 0.f};

    gemm_ring3<HID>(Ab, W, (size_t)I2, gcol, pcl, acc, lds, t, lane, wr, wc);

    const int cl = lane & 15;
    const int r0 = (lane >> 4) << 2;
#pragma unroll
    for (int mf = 0; mf < 4; ++mf)
#pragma unroll
        for (int nf = 0; nf < 4; ++nf)
#pragma unroll
            for (int r = 0; r < 4; ++r) {
                float v  = acc[mf][nf][r];
                float pv = __shfl_xor(v, 1);
                if ((lane & 1) == 0) {
                    float s = v / (1.f + __expf(-v)) * pv;
                    int row = m0 + wr + mf * 16 + r0 + r;
                    int pcc = n0 + wc + nf * 16 + cl;
                    int c   = pcc >> 1;
                    int c2  = (c & ~31) | ((c & 31) ^ G2(row));  // fc2-A swizzle
                    inter[(size_t)row * INTER + c2] = f2bf(s);
                }
            }
}

// fc2: inter(bf16 ws) @ w2(fp32 native [I][H]) -> out fp32
__global__ __launch_bounds__(512, 4) void k_fc2_r4(const unsigned short* __restrict__ A,
                                                   const float* __restrict__ W2,
                                                   float* __restrict__ out) {
    extern __shared__ unsigned short lds[];
    const int bid = blockIdx.x;                // 512 = 8 XCD * (4 mt * 16 nt)
    const int e   = bid & 7;
    const int idx = bid >> 3;
    const int mt  = idx & 3;
    const int nt  = idx >> 2;                  // 0..15
    const int t = threadIdx.x, lane = t & 63, w = t >> 6;
    const int wr = (w >> 1) * 64;
    const int wc = (w & 1) * 64;
    const int m0 = e * TOK + mt * 256;
    const int n0 = nt * 128;
    const unsigned short* Ab = A + (size_t)m0 * INTER;
    const float* W = W2 + (size_t)e * INTER * HID;
    const int tc   = t & 127;
    const int gcol = n0 + tc;                  // already coalesced
    const int pcl  = tc;

    f32x4 acc[4][4];
#pragma unroll
    for (int i = 0; i < 4; ++i)
#pragma unroll
        for (int j = 0; j < 4; ++j) acc[i][j] = f32x4{0.f, 0.f, 0.f, 0.f};

    gemm_ring3<INTER>(Ab, W, (size_t)HID, gcol, pcl, acc, lds, t, lane, wr, wc);

    const int cl = lane & 15;
    const int r0 = (lane >> 4) << 2;
#pragma unroll
    for (int mf = 0; mf < 4; ++mf)
#pragma unroll
        for (int nf = 0; nf < 4; ++nf)
#pragma unroll
            for (int r = 0; r < 4; ++r) {
                int row = m0 + wr + mf * 16 + r0 + r;
                int col = n0 + wc + nf * 16 + cl;
                out[(size_t)row * HID + col] = acc[mf][nf][r];
            }
}

// ---------------- fallback (round-1 kernels, need only 92 MB ws) ----------------

#define BM  128
#define BK  64
#define LDK 72

__global__ __launch_bounds__(256) void k_fc1_glu_fb(
    const float* __restrict__ X, const float* __restrict__ W1,
    unsigned short* __restrict__ inter)
{
    __shared__ unsigned short As[BM][LDK];
    __shared__ unsigned short Bs[128][LDK];
    const int bid = blockIdx.x;
    const int nt  = bid % (INTER / 64);
    const int mt  = (bid / (INTER / 64)) % (TOK / BM);
    const int e   = bid / ((INTER / 64) * (TOK / BM));
    const int t = threadIdx.x, lane = t & 63, w = t >> 6;
    const int m0 = mt * BM;
    const int rowbase = e * TOK + m0;
    f32x4 acc[2][8];
#pragma unroll
    for (int i = 0; i < 2; ++i)
#pragma unroll
        for (int jj = 0; jj < 8; ++jj) acc[i][jj] = f32x4{0.f, 0.f, 0.f, 0.f};
    const int jcol = t & 127;
    const int hf   = t >> 7;
    const int gcol = (jcol < 64) ? (nt * 64 + jcol) : (INTER + nt * 64 + (jcol - 64));
    const float* w1e = W1 + (size_t)e * HID * I2;
    for (int k0 = 0; k0 < HID; k0 += BK) {
#pragma unroll
        for (int it = 0; it < 8; ++it) {
            int lin = it * 256 + t;
            int r   = lin >> 4;
            int kq  = (lin & 15) << 2;
            const float4 v = *reinterpret_cast<const float4*>(
                X + (size_t)(rowbase + r) * HID + k0 + kq);
            ushort4 o;
            o.x = f2bf(v.x); o.y = f2bf(v.y); o.z = f2bf(v.z); o.w = f2bf(v.w);
            *reinterpret_cast<ushort4*>(&As[r][kq]) = o;
        }
#pragma unroll
        for (int it = 0; it < 8; ++it) {
            int kq = hf * 4 + it * 8;
            const float* p = w1e + (size_t)(k0 + kq) * I2 + gcol;
            float v0 = p[0], v1 = p[I2], v2 = p[2 * I2], v3 = p[3 * I2];
            ushort4 o;
            o.x = f2bf(v0); o.y = f2bf(v1); o.z = f2bf(v2); o.w = f2bf(v3);
            *reinterpret_cast<ushort4*>(&Bs[jcol][kq]) = o;
        }
        __syncthreads();
#pragma unroll
        for (int kk = 0; kk < 2; ++kk) {
            const int kb = kk * 32 + ((lane >> 4) << 3);
            bf16x8 a0 = *reinterpret_cast<const bf16x8*>(&As[w * 32 + (lane & 15)][kb]);
            bf16x8 a1 = *reinterpret_cast<const bf16x8*>(&As[w * 32 + 16 + (lane & 15)][kb]);
#pragma unroll
            for (int nf = 0; nf < 8; ++nf) {
                bf16x8 b = *reinterpret_cast<const bf16x8*>(&Bs[nf * 16 + (lane & 15)][kb]);
                acc[0][nf] = MFMA_BF16(a0, b, acc[0][nf]);
                acc[1][nf] = MFMA_BF16(a1, b, acc[1][nf]);
            }
        }
        __syncthreads();
    }
    const int rl0 = w * 32 + ((lane >> 4) << 2);
    const int cl  = lane & 15;
#pragma unroll
    for (int mf = 0; mf < 2; ++mf)
#pragma unroll
        for (int nfa = 0; nfa < 4; ++nfa) {
            f32x4 va = acc[mf][nfa];
            f32x4 vb = acc[mf][nfa + 4];
#pragma unroll
            for (int r = 0; r < 4; ++r) {
                float a = va[r], b = vb[r];
                float s = a / (1.f + __expf(-a)) * b;
                int row = rowbase + rl0 + mf * 16 + r;
                int col = nt * 64 + nfa * 16 + cl;
                inter[(size_t)row * INTER + col] = f2bf(s);
            }
        }
}

__global__ __launch_bounds__(256) void k_fc2_fb(
    const unsigned short* __restrict__ inter, const float* __restrict__ W2,
    float* __restrict__ out)
{
    __shared__ unsigned short As[BM][LDK];
    __shared__ unsigned short Bs[128][LDK];
    const int bid = blockIdx.x;
    const int nt  = bid % (HID / 128);
    const int mt  = (bid / (HID / 128)) % (TOK / BM);
    const int e   = bid / ((HID / 128) * (TOK / BM));
    const int t = threadIdx.x, lane = t & 63, w = t >> 6;
    const int m0 = mt * BM;
    const int rowbase = e * TOK + m0;
    f32x4 acc[2][8];
#pragma unroll
    for (int i = 0; i < 2; ++i)
#pragma unroll
        for (int jj = 0; jj < 8; ++jj) acc[i][jj] = f32x4{0.f, 0.f, 0.f, 0.f};
    const int jcol = t & 127;
    const int hf   = t >> 7;
    const int gcol = nt * 128 + jcol;
    const float* w2e = W2 + (size_t)e * INTER * HID;
    for (int k0 = 0; k0 < INTER; k0 += BK) {
#pragma unroll
        for (int it = 0; it < 4; ++it) {
            int lin = it * 256 + t;
            int r   = lin >> 3;
            int kq  = (lin & 7) << 3;
            uint4 v = *reinterpret_cast<const uint4*>(
                inter + (size_t)(rowbase + r) * INTER + k0 + kq);
            *reinterpret_cast<uint4*>(&As[r][kq]) = v;
        }
#pragma unroll
        for (int it = 0; it < 8; ++it) {
            int kq = hf * 4 + it * 8;
            const float* p = w2e + (size_t)(k0 + kq) * HID + gcol;
            float v0 = p[0], v1 = p[HID], v2 = p[2 * HID], v3 = p[3 * HID];
            ushort4 o;
            o.x = f2bf(v0); o.y = f2bf(v1); o.z = f2bf(v2); o.w = f2bf(v3);
            *reinterpret_cast<ushort4*>(&Bs[jcol][kq]) = o;
        }
        __syncthreads();
#pragma unroll
        for (int kk = 0; kk < 2; ++kk) {
            const int kb = kk * 32 + ((lane >> 4) << 3);
            bf16x8 a0 = *reinterpret_cast<const bf16x8*>(&As[w * 32 + (lane & 15)][kb]);
            bf16x8 a1 = *reinterpret_cast<const bf16x8*>(&As[w * 32 + 16 + (lane & 15)][kb]);
#pragma unroll
            for (int nf = 0; nf < 8; ++nf) {
                bf16x8 b = *reinterpret_cast<const bf16x8*>(&Bs[nf * 16 + (lane & 15)][kb]);
                acc[0][nf] = MFMA_BF16(a0, b, acc[0][nf]);
                acc[1][nf] = MFMA_BF16(a1, b, acc[1][nf]);
            }
        }
        __syncthreads();
    }
    const int rl0 = w * 32 + ((lane >> 4) << 2);
    const int cl  = lane & 15;
#pragma unroll
    for (int mf = 0; mf < 2; ++mf)
#pragma unroll
        for (int nf = 0; nf < 8; ++nf) {
            f32x4 v = acc[mf][nf];
#pragma unroll
            for (int r = 0; r < 4; ++r) {
                int row = rowbase + rl0 + mf * 16 + r;
                int col = nt * 128 + nf * 16 + cl;
                out[(size_t)row * HID + col] = v[r];
            }
        }
}

// ---------------- launch ----------------

extern "C" void kernel_launch(void* const* d_in, const int* in_sizes, int n_in,
                              void* d_out, int out_size, void* d_ws, size_t ws_size,
                              hipStream_t stream) {
    const float* X  = (const float*)d_in[0];
    const float* W1 = (const float*)d_in[1];
    const float* W2 = (const float*)d_in[2];
    float* out = (float*)d_out;

    const size_t XB_B  = (size_t)EXPERTS * TOK * HID * 2;        // 33.5 MB
    const size_t INT_B = (size_t)EXPERTS * TOK * INTER * 2;      // 92.3 MB
    const size_t need  = XB_B + INT_B;

    if (ws_size >= need) {
        unsigned short* Xb    = (unsigned short*)d_ws;
        unsigned short* inter = (unsigned short*)((char*)d_ws + XB_B);

        hipFuncSetAttribute((const void*)k_fc1_r4,
            hipFuncAttributeMaxDynamicSharedMemorySize, 73728);
        hipFuncSetAttribute((const void*)k_fc2_r4,
            hipFuncAttributeMaxDynamicSharedMemorySize, 73728);

        dim3 b256(256), b512(512);
        k_cvt_x <<<(EXPERTS * TOK * HID) / (256 * 8), b256, 0, stream>>>(X, Xb);
        k_fc1_r4<<<EXPERTS * 4 * (I2 / 128),  b512, 73728, stream>>>(Xb, W1, inter);
        k_fc2_r4<<<EXPERTS * 4 * (HID / 128), b512, 73728, stream>>>(inter, W2, out);
    } else {
        unsigned short* inter = (unsigned short*)d_ws;
        dim3 b256(256);
        k_fc1_glu_fb<<<EXPERTS * (TOK / BM) * (INTER / 64), b256, 0, stream>>>(X, W1, inter);
        k_fc2_fb    <<<EXPERTS * (TOK / BM) * (HID / 128),  b256, 0, stream>>>(inter, W2, out);
    }
}